// Round 2
// baseline (266.183 us; speedup 1.0000x reference)
//
#include <hip/hip_runtime.h>
#include <hip/hip_bf16.h>

// Slot Attention fwd, B=8 N=2048 D=256 S=8 H=256 ITERS=3.  All f32.
// Identity used: k/v are never materialized.
//   dots[b,s,n] = SCALE*( sum_d xn[b,n,d]*qg[b,s,d] + qc[b,s] )
//     qg[b,s,d] = g_in[s,d] * sum_o q[b,s,o]*Wk[s,o,d],  qc = sum_o q*ck,
//     ck[s,o]   = sum_d b_in[s,d]*Wk[s,o,d] + bk[s,o]
//   updates[b,s,o] = (sum_d axun[b,s,d]*g_in[s,d]*Wv[s,o,d])/rowsum[b,s] + cv[s,o]
//     axun = sum_n attn_ori * xn,  rowsum = sum_n attn_ori, sum_n attn == 1.
// xn (= LN(inputs)) is NOT stored: k_dots recomputes LN while staging tiles.

#define BB 8
#define NT 2048
#define DD 256
#define SS 8
#define HH 256

static constexpr float F_EPS   = 1e-8f;
static constexpr float F_LNEPS = 1e-5f;
static constexpr float F_SCALE = 0.0625f;   // 256^-0.5

__device__ __forceinline__ float wredsum(float v) {
#pragma unroll
  for (int m = 32; m > 0; m >>= 1) v += __shfl_xor(v, m, 64);
  return v;
}
__device__ __forceinline__ float sigm(float x) { return 1.f / (1.f + __expf(-x)); }
__device__ __forceinline__ float tanhfast(float x) {
  float ax = fabsf(x);
  float e = __expf(2.f * ax);
  float t = 1.f - 2.f / (e + 1.f);
  return x < 0.f ? -t : t;
}

// ---------------- init: ck/cv and slots ----------------
__global__ __launch_bounds__(256) void k_init(
    const float* __restrict__ Wk, const float* __restrict__ bk,
    const float* __restrict__ Wv, const float* __restrict__ bv,
    const float* __restrict__ b_in, const float* __restrict__ smu,
    const float* __restrict__ slsig, const float* __restrict__ noise,
    float* __restrict__ ck, float* __restrict__ cv, float* __restrict__ slots) {
  int blk = blockIdx.x;
  int t = threadIdx.x;
  if (blk < 32) {
    int s = blk >> 2, oq = blk & 3;
    int wid = t >> 6, lane = t & 63;
    float4 bi = ((const float4*)(b_in + s*DD))[lane];
    for (int r = 0; r < 16; ++r) {
      int o = oq*64 + wid*16 + r;
      float4 wk4 = ((const float4*)(Wk + ((size_t)s*DD + o)*DD))[lane];
      float4 wv4 = ((const float4*)(Wv + ((size_t)s*DD + o)*DD))[lane];
      float pk = wredsum(bi.x*wk4.x + bi.y*wk4.y + bi.z*wk4.z + bi.w*wk4.w);
      float pv = wredsum(bi.x*wv4.x + bi.y*wv4.y + bi.z*wv4.z + bi.w*wv4.w);
      if (lane == 0) {
        ck[s*DD+o] = pk + bk[s*DD+o];
        cv[s*DD+o] = pv + bv[s*DD+o];
      }
    }
  } else {
    int idx = (blk-32)*256 + t;       // < B*S*D
    int sd = idx & 2047;
    slots[idx] = smu[sd] + __expf(slsig[sd]) * noise[idx];
  }
}

// ---------------- per-(b,s): sn=LN(slots), q, qg, qc; zero accumulators ----------------
__global__ __launch_bounds__(256) void k_q(
    const float* __restrict__ slots, const float* __restrict__ g_ns,
    const float* __restrict__ b_ns, const float* __restrict__ Wq,
    const float* __restrict__ bq, const float* __restrict__ Wk,
    const float* __restrict__ ck, const float* __restrict__ g_in,
    float* __restrict__ qg, float* __restrict__ qc,
    float* __restrict__ axun, float* __restrict__ rsum) {
  __shared__ __align__(16) float sn[DD];
  __shared__ float qv[DD];
  __shared__ float red[8];
  int bs = blockIdx.x;          // b*8+s
  int s = bs & 7;
  int t = threadIdx.x;
  int wid = t >> 6, lane = t & 63;
  float x = slots[(size_t)bs*DD + t];
  float sv = wredsum(x);
  float sq = wredsum(x*x);
  if (lane == 0) { red[wid] = sv; red[4+wid] = sq; }
  axun[(size_t)bs*DD + t] = 0.f;            // zero accumulators for k_dots
  if (t == 0) rsum[bs] = 0.f;
  __syncthreads();
  sv = red[0]+red[1]+red[2]+red[3];
  sq = red[4]+red[5]+red[6]+red[7];
  float mu = sv*(1.f/DD), var = sq*(1.f/DD)-mu*mu, rs = rsqrtf(var+F_LNEPS);
  sn[t] = (x-mu)*rs*g_ns[s*DD+t] + b_ns[s*DD+t];
  __syncthreads();
  const float4* snv = (const float4*)sn;
  float4 s4 = snv[lane];
  for (int r = 0; r < 64; ++r) {          // wave per q-row
    int o = wid*64 + r;
    float4 w4 = ((const float4*)(Wq + ((size_t)s*DD + o)*DD))[lane];
    float p = wredsum(w4.x*s4.x + w4.y*s4.y + w4.z*s4.z + w4.w*s4.w);
    if (lane == 0) qv[o] = p + bq[s*DD+o];
  }
  __syncthreads();
  float acc = 0.f;                        // qg: thread t = d, coalesced Wk column walk
#pragma unroll 8
  for (int o = 0; o < DD; ++o) acc += qv[o] * Wk[((size_t)s*DD + o)*DD + t];
  qg[(size_t)bs*DD + t] = acc * g_in[s*DD + t];
  float pc = wredsum(qv[t] * ck[s*DD + t]);
  if (lane == 0) red[wid] = pc;
  __syncthreads();
  if (t == 0) qc[bs] = red[0]+red[1]+red[2]+red[3];
}

// ---------------- heavy: LN(inputs) + dots + softmax(slots) + rowsum + ax ----------------
__global__ __launch_bounds__(256) void k_dots(
    const float* __restrict__ inputs, const float* __restrict__ qg,
    const float* __restrict__ qc, float* __restrict__ axun,
    float* __restrict__ rsum, float* __restrict__ attn_out, int write_attn) {
  __shared__ __align__(16) float qgl[SS*DD];   // 8 KB
  __shared__ __align__(16) float xt[32*260];   // 33.3 KB, padded stride 260
  __shared__ float dl[8*33];
  __shared__ float qcl[8];
  __shared__ float rsl[8];
  int t = threadIdx.x;
  int b = blockIdx.x >> 5;
  int chunk = blockIdx.x & 31;                 // 32 chunks x 64 n = 2048
  int wid = t >> 6, lane = t & 63;
  for (int i = t; i < SS*DD; i += 256) qgl[i] = qg[(size_t)b*SS*DD + i];
  if (t < 8) { qcl[t] = qc[b*8+t]; rsl[t] = 0.f; }
  int si = t >> 5, ni = t & 31;
  float axa[8] = {0.f,0.f,0.f,0.f,0.f,0.f,0.f,0.f};
  for (int tile = 0; tile < 2; ++tile) {
    int n0 = (chunk*2 + tile) * 32;
    __syncthreads();
    // stage 32 rows: wave per row, LN fused (recompute of xn)
#pragma unroll
    for (int rr = 0; rr < 8; ++rr) {
      int r = wid*8 + rr;
      const float4* src = (const float4*)(inputs + ((size_t)b*NT + n0 + r)*DD);
      float4 x = src[lane];
      float sv = wredsum(x.x + x.y + x.z + x.w);
      float sq = wredsum(x.x*x.x + x.y*x.y + x.z*x.z + x.w*x.w);
      float mu = sv*(1.f/DD), var = sq*(1.f/DD)-mu*mu, rs = rsqrtf(var+F_LNEPS);
      float4 o;
      o.x=(x.x-mu)*rs; o.y=(x.y-mu)*rs; o.z=(x.z-mu)*rs; o.w=(x.w-mu)*rs;
      *(float4*)&xt[r*260 + lane*4] = o;
    }
    __syncthreads();
    float acc = 0.f;
    {
      const float4* xr = (const float4*)&xt[ni*260];
      const float4* qr = (const float4*)&qgl[si*DD];
#pragma unroll 8
      for (int j = 0; j < 64; ++j) {
        float4 a4 = xr[j]; float4 b4 = qr[j];
        acc += a4.x*b4.x + a4.y*b4.y + a4.z*b4.z + a4.w*b4.w;
      }
    }
    float dot = (acc + qcl[si]) * F_SCALE;
    dl[si*33+ni] = dot;
    __syncthreads();
    float m = dl[ni];
#pragma unroll
    for (int ss2 = 1; ss2 < 8; ++ss2) m = fmaxf(m, dl[ss2*33+ni]);
    float den = 0.f;
#pragma unroll
    for (int ss2 = 0; ss2 < 8; ++ss2) den += __expf(dl[ss2*33+ni] - m);
    float a = __expf(dot - m) / den + F_EPS;
    __syncthreads();
    dl[si*33+ni] = a;                          // dl now holds attn_ori
    float rv = a;
#pragma unroll
    for (int mm = 16; mm > 0; mm >>= 1) rv += __shfl_xor(rv, mm, 64);
    if (ni == 0) rsl[si] += rv;
    if (write_attn) attn_out[(size_t)(b*8+si)*NT + n0 + ni] = a;
    __syncthreads();
    // ax phase: thread t = d
#pragma unroll
    for (int n = 0; n < 32; ++n) {
      float x = xt[n*260 + t];
#pragma unroll
      for (int ss2 = 0; ss2 < 8; ++ss2) axa[ss2] += dl[ss2*33+n] * x;
    }
  }
#pragma unroll
  for (int ss2 = 0; ss2 < 8; ++ss2)
    atomicAdd(&axun[(size_t)(b*8+ss2)*DD + t], axa[ss2]);
  __syncthreads();
  if (t < 8) atomicAdd(&rsum[b*8+t], rsl[t]);
}

// ---------------- batched-over-B 32-row GEMV core ----------------
// X2 LDS layout: (b,d) -> b*288 + (d>>5)*36 + (d&31)   (bank-conflict-free)
__device__ __forceinline__ int x2i(int bb, int dd) { return bb*288 + (dd>>5)*36 + (dd&31); }

template <typename F>
__device__ __forceinline__ void gemv32(const float* __restrict__ Wrow0,
                                       const float* __restrict__ X2,
                                       float* __restrict__ part, F emit) {
  int t = threadIdx.x;
  int ol = t >> 3, dg = t & 7;
  const float4* wr = (const float4*)(Wrow0 + (size_t)ol*256 + (size_t)dg*32);
  __syncthreads();                 // X2 staged / part free
  float acc[8] = {0.f,0.f,0.f,0.f,0.f,0.f,0.f,0.f};
#pragma unroll
  for (int j = 0; j < 8; ++j) {
    float4 w4 = wr[j];
    int xo = dg*36 + 4*j;
#pragma unroll
    for (int bbi = 0; bbi < 8; ++bbi) {
      float4 x4 = *(const float4*)&X2[bbi*288 + xo];
      acc[bbi] = fmaf(w4.x,x4.x, fmaf(w4.y,x4.y, fmaf(w4.z,x4.z, fmaf(w4.w,x4.w, acc[bbi]))));
    }
  }
#pragma unroll
  for (int bbi = 0; bbi < 8; ++bbi) part[(ol*8+bbi)*9 + dg] = acc[bbi];
  __syncthreads();
  int o = t >> 3, bbo = t & 7;
  const float* p = &part[(o*8+bbo)*9];
  float v = ((p[0]+p[1])+(p[2]+p[3]))+((p[4]+p[5])+(p[6]+p[7]));
  emit(o, bbo, v);
}

// ---------------- updates (Wv) and gh (W_hh) ----------------
__global__ __launch_bounds__(256) void k_upd_gh(
    const float* __restrict__ axun, const float* __restrict__ rsum,
    const float* __restrict__ g_in, const float* __restrict__ Wv,
    const float* __restrict__ cv, const float* __restrict__ Whh,
    const float* __restrict__ bhh, const float* __restrict__ slots,
    float* __restrict__ upd, float* __restrict__ ghb) {
  __shared__ __align__(16) float X2[8*288];
  __shared__ float part[32*8*9];
  int blk = blockIdx.x;
  int s = blk >> 5, rc = blk & 31;
  int t = threadIdx.x;
  if (rc < 8) {
    for (int i = t; i < 2048; i += 256) {
      int bb2 = i >> 8, dd = i & 255;
      X2[x2i(bb2,dd)] = axun[(size_t)(bb2*8+s)*DD + dd] / rsum[bb2*8+s] * g_in[s*DD+dd];
    }
    int ob = rc*32;
    gemv32(Wv + ((size_t)s*DD + ob)*DD, X2, part, [&](int o,int bb2,float v){
      upd[(size_t)(bb2*8+s)*DD + ob + o] = v + cv[s*DD + ob + o];
    });
  } else {
    for (int i = t; i < 2048; i += 256) {
      int bb2 = i >> 8, dd = i & 255;
      X2[x2i(bb2,dd)] = slots[(size_t)(bb2*8+s)*DD + dd];
    }
    int ob = (rc-8)*32;
    gemv32(Whh + ((size_t)s*768 + ob)*DD, X2, part, [&](int o,int bb2,float v){
      ghb[(size_t)(bb2*8+s)*768 + ob + o] = v + bhh[s*768 + ob + o];
    });
  }
}

// ---------------- gi (W_ih) + GRU elementwise ----------------
__global__ __launch_bounds__(256) void k_gru(
    const float* __restrict__ upd, const float* __restrict__ Wih,
    const float* __restrict__ bih, const float* __restrict__ ghb,
    const float* __restrict__ slots, float* __restrict__ smid) {
  __shared__ __align__(16) float X2[8*288];
  __shared__ float part[32*8*9];
  int blk = blockIdx.x;
  int s = blk >> 3, jc = blk & 7;
  int t = threadIdx.x;
  for (int i = t; i < 2048; i += 256) {
    int bb2 = i >> 8, dd = i & 255;
    X2[x2i(bb2,dd)] = upd[(size_t)(bb2*8+s)*DD + dd];
  }
  int jb = jc*32;
  float gir = 0.f, giz = 0.f, gin = 0.f;
  gemv32(Wih + ((size_t)s*768 + jb)*DD, X2, part,
         [&](int o,int bb2,float v){ (void)o; (void)bb2; gir = v + bih[s*768 + jb + (threadIdx.x>>3)]; });
  gemv32(Wih + ((size_t)s*768 + 256 + jb)*DD, X2, part,
         [&](int o,int bb2,float v){ (void)o; (void)bb2; giz = v + bih[s*768 + 256 + jb + (threadIdx.x>>3)]; });
  gemv32(Wih + ((size_t)s*768 + 512 + jb)*DD, X2, part,
         [&](int o,int bb2,float v){ (void)o; (void)bb2; gin = v + bih[s*768 + 512 + jb + (threadIdx.x>>3)]; });
  int j = t >> 3, bb2 = t & 7;       // same (o,b) mapping as gemv32 emit
  size_t gb = (size_t)(bb2*8+s)*768 + jb + j;
  float r = sigm(gir + ghb[gb]);
  float z = sigm(giz + ghb[gb+256]);
  float nn2 = tanhfast(gin + r*ghb[gb+512]);
  size_t si2 = (size_t)(bb2*8+s)*DD + jb + j;
  float sp = slots[si2];
  smid[si2] = (1.f - z)*nn2 + z*sp;
}

// ---------------- MLP layer 1: pre = LN(smid)*g_pf+b_pf ; h1 = relu(pre@W1^T+b1) ----------------
__global__ __launch_bounds__(256) void k_mlp1(
    const float* __restrict__ smid, const float* __restrict__ g_pf,
    const float* __restrict__ b_pf, const float* __restrict__ W1,
    const float* __restrict__ b1, float* __restrict__ h1b) {
  __shared__ __align__(16) float X2[8*288];
  __shared__ float part[32*8*9];
  int blk = blockIdx.x;
  int s = blk >> 3, rc = blk & 7;
  int t = threadIdx.x;
  int wid = t >> 6, lane = t & 63;
#pragma unroll
  for (int half = 0; half < 2; ++half) {
    int bb2 = wid + half*4;
    const float4* src = (const float4*)(smid + (size_t)(bb2*8+s)*DD);
    float4 x = src[lane];
    float sv = wredsum(x.x+x.y+x.z+x.w);
    float sq = wredsum(x.x*x.x + x.y*x.y + x.z*x.z + x.w*x.w);
    float mu = sv*(1.f/DD), var = sq*(1.f/DD)-mu*mu, rs = rsqrtf(var+F_LNEPS);
    float4 g4 = ((const float4*)(g_pf + s*DD))[lane];
    float4 p4 = ((const float4*)(b_pf + s*DD))[lane];
    int d0 = lane*4;
    int base = bb2*288 + (d0>>5)*36 + (d0&31);
    X2[base]   = (x.x-mu)*rs*g4.x + p4.x;
    X2[base+1] = (x.y-mu)*rs*g4.y + p4.y;
    X2[base+2] = (x.z-mu)*rs*g4.z + p4.z;
    X2[base+3] = (x.w-mu)*rs*g4.w + p4.w;
  }
  gemv32(W1 + ((size_t)s*HH + rc*32)*DD, X2, part, [&](int o,int bb2,float v){
    float rr = v + b1[s*HH + rc*32 + o];
    h1b[(size_t)(bb2*8+s)*HH + rc*32 + o] = fmaxf(rr, 0.f);
  });
}

// ---------------- MLP layer 2 + residual (f32 slots out on last iter) ----------------
__global__ __launch_bounds__(256) void k_mlp2(
    const float* __restrict__ h1b, const float* __restrict__ W2,
    const float* __restrict__ b2, const float* __restrict__ smid,
    float* __restrict__ slots, float* __restrict__ out_slots, int last) {
  __shared__ __align__(16) float X2[8*288];
  __shared__ float part[32*8*9];
  int blk = blockIdx.x;
  int s = blk >> 3, rc = blk & 7;
  int t = threadIdx.x;
  for (int i = t; i < 2048; i += 256) {
    int bb2 = i >> 8, dd = i & 255;
    X2[x2i(bb2,dd)] = h1b[(size_t)(bb2*8+s)*HH + dd];
  }
  gemv32(W2 + ((size_t)s*DD + rc*32)*HH, X2, part, [&](int o,int bb2,float v){
    int d = rc*32 + o;
    size_t idx = (size_t)(bb2*8+s)*DD + d;
    float rr = v + b2[s*DD + d] + smid[idx];
    slots[idx] = rr;
    if (last) out_slots[idx] = rr;
  });
}

extern "C" void kernel_launch(void* const* d_in, const int* in_sizes, int n_in,
                              void* d_out, int out_size, void* d_ws, size_t ws_size,
                              hipStream_t stream) {
  (void)in_sizes; (void)n_in; (void)out_size; (void)ws_size;
  const float* inputs = (const float*)d_in[0];
  const float* noise  = (const float*)d_in[1];
  const float* smu    = (const float*)d_in[2];
  const float* slsig  = (const float*)d_in[3];
  const float* g_in   = (const float*)d_in[4];
  const float* b_in   = (const float*)d_in[5];
  const float* g_ns   = (const float*)d_in[6];
  const float* b_ns   = (const float*)d_in[7];
  const float* g_pf   = (const float*)d_in[8];
  const float* b_pf   = (const float*)d_in[9];
  const float* Wq  = (const float*)d_in[10];
  const float* bq  = (const float*)d_in[11];
  const float* Wk  = (const float*)d_in[12];
  const float* bk  = (const float*)d_in[13];
  const float* Wv  = (const float*)d_in[14];
  const float* bv  = (const float*)d_in[15];
  const float* Wih = (const float*)d_in[16];
  const float* bih = (const float*)d_in[17];
  const float* Whh = (const float*)d_in[18];
  const float* bhh = (const float*)d_in[19];
  const float* W1  = (const float*)d_in[20];
  const float* b1  = (const float*)d_in[21];
  const float* W2  = (const float*)d_in[22];
  const float* b2  = (const float*)d_in[23];

  float* ws = (float*)d_ws;
  float* slots  = ws;                                  // B*S*D = 16384
  float* smid   = slots + BB*SS*DD;                    // 16384
  float* ck     = smid + BB*SS*DD;                     // 2048
  float* cv     = ck + SS*DD;                          // 2048
  float* qg     = cv + SS*DD;                          // 16384
  float* qc     = qg + BB*SS*DD;                       // 64
  float* rsum   = qc + BB*SS;                          // 64
  float* axun   = rsum + BB*SS;                        // 16384
  float* upd    = axun + BB*SS*DD;                     // 16384
  float* ghb    = upd + BB*SS*DD;                      // B*S*768 = 49152
  float* h1b    = ghb + (size_t)BB*SS*768;             // B*S*H = 16384
  // total ~0.58 MB of f32 workspace

  float* out_slots = (float*)d_out;                    // f32 outputs (reference dtype)
  float* out_attn  = out_slots + BB*SS*DD;

  k_init<<<dim3(96), dim3(256), 0, stream>>>(Wk, bk, Wv, bv, b_in, smu, slsig, noise, ck, cv, slots);
  for (int it = 0; it < 3; ++it) {
    int last = (it == 2) ? 1 : 0;
    k_q<<<dim3(64), dim3(256), 0, stream>>>(slots, g_ns, b_ns, Wq, bq, Wk, ck, g_in,
                                            qg, qc, axun, rsum);
    k_dots<<<dim3(256), dim3(256), 0, stream>>>(inputs, qg, qc, axun, rsum, out_attn, last);
    k_upd_gh<<<dim3(256), dim3(256), 0, stream>>>(axun, rsum, g_in, Wv, cv, Whh, bhh,
                                                  slots, upd, ghb);
    k_gru<<<dim3(64), dim3(256), 0, stream>>>(upd, Wih, bih, ghb, slots, smid);
    k_mlp1<<<dim3(64), dim3(256), 0, stream>>>(smid, g_pf, b_pf, W1, b1, h1b);
    k_mlp2<<<dim3(64), dim3(256), 0, stream>>>(h1b, W2, b2, smid, slots, out_slots, last);
  }
}

// Round 3
// 181.882 us; speedup vs baseline: 1.4635x; 1.4635x over previous
//
#include <hip/hip_runtime.h>
#include <hip/hip_bf16.h>

// Slot Attention fwd, B=8 N=2048 D=256 S=8 H=256 ITERS=3.  All f32.
// k/v never materialized; q-chain collapsed into precomputed Pg:
//   Pg[s] = diag(g_in[s]) * Wk[s]^T Wq[s]          (iteration-invariant)
//   qg[b,s] = Pg[s]*sn[b,s] + qcon[s],  qc[b,s] = sn.vq[s] + c0[s]
//   dots[b,s,n] = SCALE*( xn[b,n,:].qg[b,s,:] + qc[b,s] )
//   updates[b,s,o] = (sum_d axun*g_in*Wv)/rowsum + cv[s,o]
// xn = LN(inputs) recomputed on the fly in k_dots (never stored).

#define BB 8
#define NT 2048
#define DD 256
#define SS 8
#define HH 256

static constexpr float F_EPS   = 1e-8f;
static constexpr float F_LNEPS = 1e-5f;
static constexpr float F_SCALE = 0.0625f;   // 256^-0.5

__device__ __forceinline__ float wredsum(float v) {
#pragma unroll
  for (int m = 32; m > 0; m >>= 1) v += __shfl_xor(v, m, 64);
  return v;
}
__device__ __forceinline__ float sigm(float x) { return 1.f / (1.f + __expf(-x)); }
__device__ __forceinline__ float tanhfast(float x) {
  float ax = fabsf(x);
  float e = __expf(2.f * ax);
  float t = 1.f - 2.f / (e + 1.f);
  return x < 0.f ? -t : t;
}

// ---------------- init1: ck/cv and slots ----------------
__global__ __launch_bounds__(256) void k_init(
    const float* __restrict__ Wk, const float* __restrict__ bk,
    const float* __restrict__ Wv, const float* __restrict__ bv,
    const float* __restrict__ b_in, const float* __restrict__ smu,
    const float* __restrict__ slsig, const float* __restrict__ noise,
    float* __restrict__ ck, float* __restrict__ cv, float* __restrict__ slots) {
  int blk = blockIdx.x;
  int t = threadIdx.x;
  if (blk < 32) {
    int s = blk >> 2, oq = blk & 3;
    int wid = t >> 6, lane = t & 63;
    float4 bi = ((const float4*)(b_in + s*DD))[lane];
    for (int r = 0; r < 16; ++r) {
      int o = oq*64 + wid*16 + r;
      float4 wk4 = ((const float4*)(Wk + ((size_t)s*DD + o)*DD))[lane];
      float4 wv4 = ((const float4*)(Wv + ((size_t)s*DD + o)*DD))[lane];
      float pk = wredsum(bi.x*wk4.x + bi.y*wk4.y + bi.z*wk4.z + bi.w*wk4.w);
      float pv = wredsum(bi.x*wv4.x + bi.y*wv4.y + bi.z*wv4.z + bi.w*wv4.w);
      if (lane == 0) {
        ck[s*DD+o] = pk + bk[s*DD+o];
        cv[s*DD+o] = pv + bv[s*DD+o];
      }
    }
  } else {
    int idx = (blk-32)*256 + t;       // < B*S*D
    int sd = idx & 2047;
    slots[idx] = smu[sd] + __expf(slsig[sd]) * noise[idx];
  }
}

// ---------------- init2: Pg = diag(g_in) Wk^T Wq ; vq, qcon, c0 ----------------
__global__ __launch_bounds__(256) void k_init2(
    const float* __restrict__ Wq, const float* __restrict__ Wk,
    const float* __restrict__ bq, const float* __restrict__ ck,
    const float* __restrict__ g_in,
    float* __restrict__ Pg, float* __restrict__ vq,
    float* __restrict__ qcon, float* __restrict__ c0) {
  int blk = blockIdx.x;
  int t = threadIdx.x;
  if (blk < 512) {
    __shared__ float Ak[32*33], Aq[32*33];
    int s = blk >> 6, tile = blk & 63;
    int td = tile >> 3, te = tile & 7;
    int dl = t >> 5, el = t & 31;
    float acc[4] = {0.f,0.f,0.f,0.f};
    for (int o0 = 0; o0 < DD; o0 += 32) {
      __syncthreads();
      for (int i = t; i < 1024; i += 256) {
        int o = i >> 5, c = i & 31;
        Ak[o*33+c] = Wk[((size_t)s*DD + o0+o)*DD + td*32 + c];
        Aq[o*33+c] = Wq[((size_t)s*DD + o0+o)*DD + te*32 + c];
      }
      __syncthreads();
#pragma unroll 8
      for (int o = 0; o < 32; ++o) {
        float aq = Aq[o*33+el];
#pragma unroll
        for (int j = 0; j < 4; ++j)
          acc[j] += Ak[o*33 + dl*4 + j] * aq;
      }
    }
#pragma unroll
    for (int j = 0; j < 4; ++j) {
      int d = td*32 + dl*4 + j;
      Pg[((size_t)s*DD + d)*DD + te*32 + el] = g_in[s*DD + d] * acc[j];
    }
  } else {
    // blocks 512..527: pair (s, which): which=0 -> vq=Wq^T ck (+c0), which=1 -> qcon=g_in.(Wk^T bq)
    __shared__ float cvec[DD];
    __shared__ float part2[8*264];
    int idx = blk - 512;
    int s = idx >> 1, which = idx & 1;
    const float* W = which ? Wk : Wq;
    const float* vec = which ? bq : ck;
    cvec[t] = vec[s*DD + t];
    __syncthreads();
    int og = t >> 5, eg = t & 31;
    float acc[8] = {0.f,0.f,0.f,0.f,0.f,0.f,0.f,0.f};
    for (int oi = 0; oi < 32; ++oi) {
      int o = og*32 + oi;
      float cv2 = cvec[o];
      const float4* wrow = (const float4*)(W + ((size_t)s*DD + o)*DD + eg*8);
      float4 w0 = wrow[0], w1 = wrow[1];
      acc[0] += w0.x*cv2; acc[1] += w0.y*cv2; acc[2] += w0.z*cv2; acc[3] += w0.w*cv2;
      acc[4] += w1.x*cv2; acc[5] += w1.y*cv2; acc[6] += w1.z*cv2; acc[7] += w1.w*cv2;
    }
#pragma unroll
    for (int j = 0; j < 8; ++j) part2[og*264 + eg*8 + j] = acc[j];
    __syncthreads();
    float v = 0.f;
#pragma unroll
    for (int og2 = 0; og2 < 8; ++og2) v += part2[og2*264 + t];
    if (which) qcon[s*DD + t] = v * g_in[s*DD + t];
    else       vq[s*DD + t]   = v;
    if (which == 0 && t < 64) {
      float4 b4 = ((const float4*)(bq + s*DD))[t];
      float4 c4 = ((const float4*)(ck + s*DD))[t];
      float vv = wredsum(b4.x*c4.x + b4.y*c4.y + b4.z*c4.z + b4.w*c4.w);
      if (t == 0) c0[s] = vv;
    }
  }
}

// ---------------- batched-over-B 32-row GEMV core ----------------
// X2 LDS layout: (b,d) -> b*288 + (d>>5)*36 + (d&31)   (bank-conflict-free)
__device__ __forceinline__ int x2i(int bb, int dd) { return bb*288 + (dd>>5)*36 + (dd&31); }

template <typename F>
__device__ __forceinline__ void gemv32(const float* __restrict__ Wrow0,
                                       const float* __restrict__ X2,
                                       float* __restrict__ part, F emit) {
  int t = threadIdx.x;
  int ol = t >> 3, dg = t & 7;
  const float4* wr = (const float4*)(Wrow0 + (size_t)ol*256 + (size_t)dg*32);
  __syncthreads();                 // X2 staged / part free
  float acc[8] = {0.f,0.f,0.f,0.f,0.f,0.f,0.f,0.f};
#pragma unroll
  for (int j = 0; j < 8; ++j) {
    float4 w4 = wr[j];
    int xo = dg*36 + 4*j;
#pragma unroll
    for (int bbi = 0; bbi < 8; ++bbi) {
      float4 x4 = *(const float4*)&X2[bbi*288 + xo];
      acc[bbi] = fmaf(w4.x,x4.x, fmaf(w4.y,x4.y, fmaf(w4.z,x4.z, fmaf(w4.w,x4.w, acc[bbi]))));
    }
  }
#pragma unroll
  for (int bbi = 0; bbi < 8; ++bbi) part[(ol*8+bbi)*9 + dg] = acc[bbi];
  __syncthreads();
  int o = t >> 3, bbo = t & 7;
  const float* p = &part[(o*8+bbo)*9];
  float v = ((p[0]+p[1])+(p[2]+p[3]))+((p[4]+p[5])+(p[6]+p[7]));
  emit(o, bbo, v);
}

// ---------------- per-iter q-chain: sn=LN(slots); qg = Pg.sn + qcon; qc = sn.vq + c0 ----------------
__global__ __launch_bounds__(256) void k_q2(
    const float* __restrict__ slots, const float* __restrict__ g_ns,
    const float* __restrict__ b_ns, const float* __restrict__ Pg,
    const float* __restrict__ qcon, const float* __restrict__ vq,
    const float* __restrict__ c0,
    float* __restrict__ qg, float* __restrict__ qc,
    float* __restrict__ axun, float* __restrict__ rsum) {
  __shared__ __align__(16) float X2[8*288];
  __shared__ float part[32*8*9];
  int blk = blockIdx.x;
  int s = blk >> 3, rc = blk & 7;
  int t = threadIdx.x;
  int wid = t >> 6, lane = t & 63;
  float4 g4 = ((const float4*)(g_ns + s*DD))[lane];
  float4 p4 = ((const float4*)(b_ns + s*DD))[lane];
#pragma unroll
  for (int half = 0; half < 2; ++half) {
    int bb2 = wid + half*4;
    const float4* src = (const float4*)(slots + (size_t)(bb2*8+s)*DD);
    float4 x = src[lane];
    float sv = wredsum(x.x+x.y+x.z+x.w);
    float sq = wredsum(x.x*x.x + x.y*x.y + x.z*x.z + x.w*x.w);
    float mu = sv*(1.f/DD), var = sq*(1.f/DD)-mu*mu, rs = rsqrtf(var+F_LNEPS);
    int base = bb2*288 + (lane>>3)*36 + (lane&7)*4;
    X2[base]   = (x.x-mu)*rs*g4.x + p4.x;
    X2[base+1] = (x.y-mu)*rs*g4.y + p4.y;
    X2[base+2] = (x.z-mu)*rs*g4.z + p4.z;
    X2[base+3] = (x.w-mu)*rs*g4.w + p4.w;
  }
  if (rc == 0) {
    for (int i = t; i < 2048; i += 256) {
      int bb2 = i >> 8, dd = i & 255;
      axun[(size_t)(bb2*8+s)*DD + dd] = 0.f;     // zero accumulators for k_dots
    }
    if (t < 8) rsum[t*8+s] = 0.f;
  }
  __syncthreads();
  if (rc == 0) {           // qc for all 8 b's of this slot
    int b = t >> 5, l32 = t & 31;
    float v = 0.f;
#pragma unroll
    for (int j = 0; j < 8; ++j)
      v += X2[b*288 + j*36 + l32] * vq[s*DD + j*32 + l32];
#pragma unroll
    for (int m = 16; m > 0; m >>= 1) v += __shfl_xor(v, m, 64);
    if (l32 == 0) qc[b*8+s] = v + c0[s];
  }
  gemv32(Pg + ((size_t)s*DD + rc*32)*DD, X2, part, [&](int o,int bb2,float v){
    qg[(size_t)(bb2*8+s)*DD + rc*32 + o] = v + qcon[s*DD + rc*32 + o];
  });
}

// ---------------- heavy: LN(inputs) + dots + softmax(slots) + rowsum + ax ----------------
__global__ __launch_bounds__(256) void k_dots(
    const float* __restrict__ inputs, const float* __restrict__ qg,
    const float* __restrict__ qc, float* __restrict__ axun,
    float* __restrict__ rsum, float* __restrict__ attn_out, int write_attn) {
  __shared__ __align__(16) float qgl[SS*DD];   // 8 KB
  __shared__ __align__(16) float xt[32*260];   // 33.3 KB, padded stride 260
  __shared__ float dl[8*33];
  __shared__ float qcl[8];
  __shared__ float rsl[8];
  int t = threadIdx.x;
  int b = blockIdx.x >> 5;
  int chunk = blockIdx.x & 31;                 // 32 chunks x 64 n = 2048
  int wid = t >> 6, lane = t & 63;
  for (int i = t; i < SS*DD; i += 256) qgl[i] = qg[(size_t)b*SS*DD + i];
  if (t < 8) { qcl[t] = qc[b*8+t]; rsl[t] = 0.f; }
  int si = t >> 5, ni = t & 31;
  float axa[8] = {0.f,0.f,0.f,0.f,0.f,0.f,0.f,0.f};
  for (int tile = 0; tile < 2; ++tile) {
    int n0 = (chunk*2 + tile) * 32;
    __syncthreads();
    // stage 32 rows: wave per row, LN fused (recompute of xn)
#pragma unroll
    for (int rr = 0; rr < 8; ++rr) {
      int r = wid*8 + rr;
      const float4* src = (const float4*)(inputs + ((size_t)b*NT + n0 + r)*DD);
      float4 x = src[lane];
      float sv = wredsum(x.x + x.y + x.z + x.w);
      float sq = wredsum(x.x*x.x + x.y*x.y + x.z*x.z + x.w*x.w);
      float mu = sv*(1.f/DD), var = sq*(1.f/DD)-mu*mu, rs = rsqrtf(var+F_LNEPS);
      float4 o;
      o.x=(x.x-mu)*rs; o.y=(x.y-mu)*rs; o.z=(x.z-mu)*rs; o.w=(x.w-mu)*rs;
      *(float4*)&xt[r*260 + lane*4] = o;
    }
    __syncthreads();
    float acc = 0.f;
    {
      const float4* xr = (const float4*)&xt[ni*260];
      const float4* qr = (const float4*)&qgl[si*DD];
#pragma unroll 8
      for (int j = 0; j < 64; ++j) {
        float4 a4 = xr[j]; float4 b4 = qr[j];
        acc += a4.x*b4.x + a4.y*b4.y + a4.z*b4.z + a4.w*b4.w;
      }
    }
    float dot = (acc + qcl[si]) * F_SCALE;
    dl[si*33+ni] = dot;
    __syncthreads();
    float m = dl[ni];
#pragma unroll
    for (int ss2 = 1; ss2 < 8; ++ss2) m = fmaxf(m, dl[ss2*33+ni]);
    float den = 0.f;
#pragma unroll
    for (int ss2 = 0; ss2 < 8; ++ss2) den += __expf(dl[ss2*33+ni] - m);
    float a = __expf(dot - m) / den + F_EPS;
    __syncthreads();
    dl[si*33+ni] = a;                          // dl now holds attn_ori
    float rv = a;
#pragma unroll
    for (int mm = 16; mm > 0; mm >>= 1) rv += __shfl_xor(rv, mm, 64);
    if (ni == 0) rsl[si] += rv;
    if (write_attn) attn_out[(size_t)(b*8+si)*NT + n0 + ni] = a;
    __syncthreads();
    // ax phase: thread t = d
#pragma unroll
    for (int n = 0; n < 32; ++n) {
      float x = xt[n*260 + t];
#pragma unroll
      for (int ss2 = 0; ss2 < 8; ++ss2) axa[ss2] += dl[ss2*33+n] * x;
    }
  }
#pragma unroll
  for (int ss2 = 0; ss2 < 8; ++ss2)
    atomicAdd(&axun[(size_t)(b*8+ss2)*DD + t], axa[ss2]);
  __syncthreads();
  if (t < 8) atomicAdd(&rsum[b*8+t], rsl[t]);
}

// ---------------- updates (Wv) and gh (W_hh) ----------------
__global__ __launch_bounds__(256) void k_upd_gh(
    const float* __restrict__ axun, const float* __restrict__ rsum,
    const float* __restrict__ g_in, const float* __restrict__ Wv,
    const float* __restrict__ cv, const float* __restrict__ Whh,
    const float* __restrict__ bhh, const float* __restrict__ slots,
    float* __restrict__ upd, float* __restrict__ ghb) {
  __shared__ __align__(16) float X2[8*288];
  __shared__ float part[32*8*9];
  int blk = blockIdx.x;
  int s = blk >> 5, rc = blk & 31;
  int t = threadIdx.x;
  if (rc < 8) {
    for (int i = t; i < 2048; i += 256) {
      int bb2 = i >> 8, dd = i & 255;
      X2[x2i(bb2,dd)] = axun[(size_t)(bb2*8+s)*DD + dd] / rsum[bb2*8+s] * g_in[s*DD+dd];
    }
    int ob = rc*32;
    gemv32(Wv + ((size_t)s*DD + ob)*DD, X2, part, [&](int o,int bb2,float v){
      upd[(size_t)(bb2*8+s)*DD + ob + o] = v + cv[s*DD + ob + o];
    });
  } else {
    for (int i = t; i < 2048; i += 256) {
      int bb2 = i >> 8, dd = i & 255;
      X2[x2i(bb2,dd)] = slots[(size_t)(bb2*8+s)*DD + dd];
    }
    int ob = (rc-8)*32;
    gemv32(Whh + ((size_t)s*768 + ob)*DD, X2, part, [&](int o,int bb2,float v){
      ghb[(size_t)(bb2*8+s)*768 + ob + o] = v + bhh[s*768 + ob + o];
    });
  }
}

// ---------------- gi (W_ih) + GRU elementwise ----------------
__global__ __launch_bounds__(256) void k_gru(
    const float* __restrict__ upd, const float* __restrict__ Wih,
    const float* __restrict__ bih, const float* __restrict__ ghb,
    const float* __restrict__ slots, float* __restrict__ smid) {
  __shared__ __align__(16) float X2[8*288];
  __shared__ float part[32*8*9];
  int blk = blockIdx.x;
  int s = blk >> 3, jc = blk & 7;
  int t = threadIdx.x;
  for (int i = t; i < 2048; i += 256) {
    int bb2 = i >> 8, dd = i & 255;
    X2[x2i(bb2,dd)] = upd[(size_t)(bb2*8+s)*DD + dd];
  }
  int jb = jc*32;
  float gir = 0.f, giz = 0.f, gin = 0.f;
  gemv32(Wih + ((size_t)s*768 + jb)*DD, X2, part,
         [&](int o,int bb2,float v){ (void)o; (void)bb2; gir = v + bih[s*768 + jb + (threadIdx.x>>3)]; });
  gemv32(Wih + ((size_t)s*768 + 256 + jb)*DD, X2, part,
         [&](int o,int bb2,float v){ (void)o; (void)bb2; giz = v + bih[s*768 + 256 + jb + (threadIdx.x>>3)]; });
  gemv32(Wih + ((size_t)s*768 + 512 + jb)*DD, X2, part,
         [&](int o,int bb2,float v){ (void)o; (void)bb2; gin = v + bih[s*768 + 512 + jb + (threadIdx.x>>3)]; });
  int j = t >> 3, bb2 = t & 7;       // same (o,b) mapping as gemv32 emit
  size_t gb = (size_t)(bb2*8+s)*768 + jb + j;
  float r = sigm(gir + ghb[gb]);
  float z = sigm(giz + ghb[gb+256]);
  float nn2 = tanhfast(gin + r*ghb[gb+512]);
  size_t si2 = (size_t)(bb2*8+s)*DD + jb + j;
  float sp = slots[si2];
  smid[si2] = (1.f - z)*nn2 + z*sp;
}

// ---------------- MLP layer 1: pre = LN(smid)*g_pf+b_pf ; h1 = relu(pre@W1^T+b1) ----------------
__global__ __launch_bounds__(256) void k_mlp1(
    const float* __restrict__ smid, const float* __restrict__ g_pf,
    const float* __restrict__ b_pf, const float* __restrict__ W1,
    const float* __restrict__ b1, float* __restrict__ h1b) {
  __shared__ __align__(16) float X2[8*288];
  __shared__ float part[32*8*9];
  int blk = blockIdx.x;
  int s = blk >> 3, rc = blk & 7;
  int t = threadIdx.x;
  int wid = t >> 6, lane = t & 63;
#pragma unroll
  for (int half = 0; half < 2; ++half) {
    int bb2 = wid + half*4;
    const float4* src = (const float4*)(smid + (size_t)(bb2*8+s)*DD);
    float4 x = src[lane];
    float sv = wredsum(x.x+x.y+x.z+x.w);
    float sq = wredsum(x.x*x.x + x.y*x.y + x.z*x.z + x.w*x.w);
    float mu = sv*(1.f/DD), var = sq*(1.f/DD)-mu*mu, rs = rsqrtf(var+F_LNEPS);
    float4 g4 = ((const float4*)(g_pf + s*DD))[lane];
    float4 p4 = ((const float4*)(b_pf + s*DD))[lane];
    int base = bb2*288 + (lane>>3)*36 + (lane&7)*4;
    X2[base]   = (x.x-mu)*rs*g4.x + p4.x;
    X2[base+1] = (x.y-mu)*rs*g4.y + p4.y;
    X2[base+2] = (x.z-mu)*rs*g4.z + p4.z;
    X2[base+3] = (x.w-mu)*rs*g4.w + p4.w;
  }
  gemv32(W1 + ((size_t)s*HH + rc*32)*DD, X2, part, [&](int o,int bb2,float v){
    float rr = v + b1[s*HH + rc*32 + o];
    h1b[(size_t)(bb2*8+s)*HH + rc*32 + o] = fmaxf(rr, 0.f);
  });
}

// ---------------- MLP layer 2 + residual (f32 slots out on last iter) ----------------
__global__ __launch_bounds__(256) void k_mlp2(
    const float* __restrict__ h1b, const float* __restrict__ W2,
    const float* __restrict__ b2, const float* __restrict__ smid,
    float* __restrict__ slots, float* __restrict__ out_slots, int last) {
  __shared__ __align__(16) float X2[8*288];
  __shared__ float part[32*8*9];
  int blk = blockIdx.x;
  int s = blk >> 3, rc = blk & 7;
  int t = threadIdx.x;
  for (int i = t; i < 2048; i += 256) {
    int bb2 = i >> 8, dd = i & 255;
    X2[x2i(bb2,dd)] = h1b[(size_t)(bb2*8+s)*HH + dd];
  }
  gemv32(W2 + ((size_t)s*DD + rc*32)*HH, X2, part, [&](int o,int bb2,float v){
    int d = rc*32 + o;
    size_t idx = (size_t)(bb2*8+s)*DD + d;
    float rr = v + b2[s*DD + d] + smid[idx];
    slots[idx] = rr;
    if (last) out_slots[idx] = rr;
  });
}

extern "C" void kernel_launch(void* const* d_in, const int* in_sizes, int n_in,
                              void* d_out, int out_size, void* d_ws, size_t ws_size,
                              hipStream_t stream) {
  (void)in_sizes; (void)n_in; (void)out_size; (void)ws_size;
  const float* inputs = (const float*)d_in[0];
  const float* noise  = (const float*)d_in[1];
  const float* smu    = (const float*)d_in[2];
  const float* slsig  = (const float*)d_in[3];
  const float* g_in   = (const float*)d_in[4];
  const float* b_in   = (const float*)d_in[5];
  const float* g_ns   = (const float*)d_in[6];
  const float* b_ns   = (const float*)d_in[7];
  const float* g_pf   = (const float*)d_in[8];
  const float* b_pf   = (const float*)d_in[9];
  const float* Wq  = (const float*)d_in[10];
  const float* bq  = (const float*)d_in[11];
  const float* Wk  = (const float*)d_in[12];
  const float* bk  = (const float*)d_in[13];
  const float* Wv  = (const float*)d_in[14];
  const float* bv  = (const float*)d_in[15];
  const float* Wih = (const float*)d_in[16];
  const float* bih = (const float*)d_in[17];
  const float* Whh = (const float*)d_in[18];
  const float* bhh = (const float*)d_in[19];
  const float* W1  = (const float*)d_in[20];
  const float* b1  = (const float*)d_in[21];
  const float* W2  = (const float*)d_in[22];
  const float* b2  = (const float*)d_in[23];

  float* ws = (float*)d_ws;
  float* slots  = ws;                                  // 16384
  float* smid   = slots + BB*SS*DD;                    // 16384
  float* ck     = smid + BB*SS*DD;                     // 2048
  float* cv     = ck + SS*DD;                          // 2048
  float* qg     = cv + SS*DD;                          // 16384
  float* qc     = qg + BB*SS*DD;                       // 64
  float* rsum   = qc + BB*SS;                          // 64
  float* axun   = rsum + BB*SS;                        // 16384
  float* upd    = axun + BB*SS*DD;                     // 16384
  float* ghb    = upd + BB*SS*DD;                      // 49152
  float* h1b    = ghb + (size_t)BB*SS*768;             // 16384
  float* vq     = h1b + BB*SS*HH;                      // 2048
  float* qcon   = vq + SS*DD;                          // 2048
  float* c0     = qcon + SS*DD;                        // 8
  float* Pg     = c0 + 64;                             // S*D*D = 524288 (2 MB)
  // total ~2.7 MB of f32 workspace

  float* out_slots = (float*)d_out;                    // f32 outputs (reference dtype)
  float* out_attn  = out_slots + BB*SS*DD;

  k_init<<<dim3(96), dim3(256), 0, stream>>>(Wk, bk, Wv, bv, b_in, smu, slsig, noise, ck, cv, slots);
  k_init2<<<dim3(528), dim3(256), 0, stream>>>(Wq, Wk, bq, ck, g_in, Pg, vq, qcon, c0);
  for (int it = 0; it < 3; ++it) {
    int last = (it == 2) ? 1 : 0;
    k_q2<<<dim3(64), dim3(256), 0, stream>>>(slots, g_ns, b_ns, Pg, qcon, vq, c0,
                                             qg, qc, axun, rsum);
    k_dots<<<dim3(256), dim3(256), 0, stream>>>(inputs, qg, qc, axun, rsum, out_attn, last);
    k_upd_gh<<<dim3(256), dim3(256), 0, stream>>>(axun, rsum, g_in, Wv, cv, Whh, bhh,
                                                  slots, upd, ghb);
    k_gru<<<dim3(64), dim3(256), 0, stream>>>(upd, Wih, bih, ghb, slots, smid);
    k_mlp1<<<dim3(64), dim3(256), 0, stream>>>(smid, g_pf, b_pf, W1, b1, h1b);
    k_mlp2<<<dim3(64), dim3(256), 0, stream>>>(h1b, W2, b2, smid, slots, out_slots, last);
  }
}